// Round 2
// baseline (272.236 us; speedup 1.0000x reference)
//
#include <hip/hip_runtime.h>
#include <hip/hip_bf16.h>
#include <math.h>

#define LSEQ 4096
#define DIM 64
#define TWO_PI 6.28318530717958647692f

typedef __attribute__((ext_vector_type(8))) short bf16x8;
typedef __attribute__((ext_vector_type(4))) float f32x4;

// ws layout (bytes):
//   btT  bf16 [4096][128]            1,048,576 @ 0
//   ypt  bf16 [64 bh][64 d][128 k]   1,048,576 @ 1,048,576
//   ftQK fp32 [128 tbh][4][128][64] 16,777,216 @ 2,097,152
//   ftV  bf16 [64 bh][4][128][64]    4,194,304 @ 18,874,368
//   Whi  bf16 [3][128][4096]         3,145,728 @ 23,068,672
//   Wlo  bf16 [3][128][4096]         3,145,728 @ 26,214,400
//   total 29,360,128  (ws proven >= 31MB in R1)

__device__ __forceinline__ unsigned short f2bfu(float f) {
  __hip_bfloat16 h = __float2bfloat16(f);
  return *(unsigned short*)&h;
}
__device__ __forceinline__ float bfu2f(unsigned short h) {
  union { unsigned int u; float f; } z;
  z.u = ((unsigned int)h) << 16;
  return z.f;
}

// ---------------------------------------------------------------- init btT (irfft basis, bf16)
__global__ __launch_bounds__(256) void init_btT(unsigned short* __restrict__ btT) {
  int u = blockIdx.x * 256 + threadIdx.x;  // < 4096*128
  int l = u >> 7, kk = u & 127;
  int f = kk >> 1;
  float ang = (float)((f * l) & 4095) * (TWO_PI / 4096.0f);
  float s, c;
  sincosf(ang, &s, &c);
  float val = (kk & 1) ? -s : c;
  btT[u] = f2bfu(val);
}

// ---------------------------------------------------------------- init W hi/lo (DFT twiddles)
__global__ __launch_bounds__(256) void init_w(unsigned short* __restrict__ whi,
                                              unsigned short* __restrict__ wlo,
                                              const int* __restrict__ iq,
                                              const int* __restrict__ ik,
                                              const int* __restrict__ iv) {
  int u = blockIdx.x * 256 + threadIdx.x;  // < 3*128*4096
  int tensor = u >> 19;
  int rem = u & 524287;
  int row = rem >> 12;
  int l = rem & 4095;
  int m = row & 63, reim = row >> 6;
  const int* idx = (tensor == 0 ? iq : tensor == 1 ? ik : iv);
  int f = idx[m];
  float ang = (float)((f * l) & 4095) * (TWO_PI / 4096.0f);
  float s, c;
  sincosf(ang, &s, &c);
  float val = reim ? -s : c;  // e^{-i t}: re=cos, im=-sin
  __hip_bfloat16 hb = __float2bfloat16(val);
  float fh = __bfloat162float(hb);
  whi[u] = *(unsigned short*)&hb;
  wlo[u] = f2bfu(val - fh);
}

// ---------------------------------------------------------------- MFMA DFT (split-bf16)
// grid 768 = 3 tensor * 64 bh * 4 Kpart ; block 512 (8 waves, 1 M-tile/wave)
// v3: 8-wave blocks double waves/CU 12->24 (latency-bound per R1 counters).
//     W fragments global->VGPR (L2-resident); X double-buffered in LDS,
//     1 barrier/chunk, issue-early prefetch.
__global__ __launch_bounds__(512, 6) void dft_mfma(
    const float* __restrict__ q, const float* __restrict__ k,
    const float* __restrict__ v, const unsigned short* __restrict__ whi,
    const unsigned short* __restrict__ wlo, float* __restrict__ ftQK,
    unsigned short* __restrict__ ftV) {
  int b = blockIdx.x;
  int tensor = b >> 8;
  int bh = (b >> 2) & 63;
  int part = b & 3;
  const float* x =
      (tensor == 0 ? q : tensor == 1 ? k : v) + (size_t)bh * (LSEQ * DIM);
  const unsigned short* wh = whi + (size_t)tensor * 524288;
  const unsigned short* wl = wlo + (size_t)tensor * 524288;

  int t = threadIdx.x;
  int lane = t & 63, w = t >> 6;           // w 0..7 -> M rows w*16..w*16+15
  int l15 = lane & 15, qd = lane >> 4;
  int xd = t & 63, xseg = t >> 6;          // 8 X rows per thread

  __shared__ __align__(16) unsigned short Xh[2][64 * 72];
  __shared__ __align__(16) unsigned short Xl[2][64 * 72];

  f32x4 acc[4];
#pragma unroll
  for (int nt = 0; nt < 4; ++nt) acc[nt] = (f32x4){0.f, 0.f, 0.f, 0.f};

  bool split = (tensor != 2);
  int k0 = part * 1024;

  // per-lane W fragment base: row = w*16 + l15, col qd*8 (+lc+ks*32)
  const unsigned short* wrh = wh + (size_t)(w * 16 + l15) * 4096 + qd * 8;
  const unsigned short* wrl = wl + (size_t)(w * 16 + l15) * 4096 + qd * 8;

  float xv[8];

  // convert xv -> hi/lo bf16 and store to buffer `buf`
  auto cvstore = [&](int buf) {
    __align__(16) unsigned short hs[8];
    __align__(16) unsigned short ls[8];
#pragma unroll
    for (int i = 0; i < 8; ++i) {
      __hip_bfloat16 hb = __float2bfloat16(xv[i]);
      hs[i] = *(unsigned short*)&hb;
      float fh = __bfloat162float(hb);
      ls[i] = f2bfu(xv[i] - fh);
    }
    *(bf16x8*)&Xh[buf][xd * 72 + xseg * 8] = *(bf16x8*)&hs[0];
    *(bf16x8*)&Xl[buf][xd * 72 + xseg * 8] = *(bf16x8*)&ls[0];
  };

  // prologue: chunk 0 -> buf 0
  {
    const float* xp = x + (size_t)(k0 + xseg * 8) * 64 + xd;
#pragma unroll
    for (int i = 0; i < 8; ++i) xv[i] = xp[(size_t)i * 64];
  }
  cvstore(0);

  for (int ch = 0; ch < 16; ++ch) {
    int lc = k0 + ch * 64;
    int cur = ch & 1;

    // W fragments for this chunk: issue FIRST so the MFMA's vmcnt wait on them
    // does not drain the X prefetch issued below.
    bf16x8 afh[2], afl[2];
#pragma unroll
    for (int ks = 0; ks < 2; ++ks)
      afh[ks] = *(const bf16x8*)(wrh + lc + ks * 32);
    if (split) {
#pragma unroll
      for (int ks = 0; ks < 2; ++ks)
        afl[ks] = *(const bf16x8*)(wrl + lc + ks * 32);
    }

    // prefetch next X chunk into registers (completes under the MFMAs)
    if (ch < 15) {
      const float* xp = x + (size_t)(lc + 64 + xseg * 8) * 64 + xd;
#pragma unroll
      for (int i = 0; i < 8; ++i) xv[i] = xp[(size_t)i * 64];
    }

    __syncthreads();  // buf[cur] fully staged by all waves

    if (split) {
#pragma unroll
      for (int ks = 0; ks < 2; ++ks) {
        bf16x8 bh_[4], bl_[4];
#pragma unroll
        for (int nt = 0; nt < 4; ++nt) {
          bh_[nt] =
              *(const bf16x8*)&Xh[cur][(nt * 16 + l15) * 72 + ks * 32 + qd * 8];
          bl_[nt] =
              *(const bf16x8*)&Xl[cur][(nt * 16 + l15) * 72 + ks * 32 + qd * 8];
        }
#pragma unroll
        for (int nt = 0; nt < 4; ++nt) {
          acc[nt] = __builtin_amdgcn_mfma_f32_16x16x32_bf16(
              afh[ks], bh_[nt], acc[nt], 0, 0, 0);
          acc[nt] = __builtin_amdgcn_mfma_f32_16x16x32_bf16(
              afh[ks], bl_[nt], acc[nt], 0, 0, 0);
          acc[nt] = __builtin_amdgcn_mfma_f32_16x16x32_bf16(
              afl[ks], bh_[nt], acc[nt], 0, 0, 0);
        }
      }
    } else {
#pragma unroll
      for (int ks = 0; ks < 2; ++ks) {
        bf16x8 bh_[4], bl_[4];
#pragma unroll
        for (int nt = 0; nt < 4; ++nt) {
          bh_[nt] =
              *(const bf16x8*)&Xh[cur][(nt * 16 + l15) * 72 + ks * 32 + qd * 8];
          bl_[nt] =
              *(const bf16x8*)&Xl[cur][(nt * 16 + l15) * 72 + ks * 32 + qd * 8];
        }
#pragma unroll
        for (int nt = 0; nt < 4; ++nt) {
          acc[nt] = __builtin_amdgcn_mfma_f32_16x16x32_bf16(
              afh[ks], bh_[nt], acc[nt], 0, 0, 0);
          acc[nt] = __builtin_amdgcn_mfma_f32_16x16x32_bf16(
              afh[ks], bl_[nt], acc[nt], 0, 0, 0);
        }
      }
    }

    // write next chunk into the other buffer (read side of next iter is
    // protected by the barrier at the top of iter ch+1)
    if (ch < 15) cvstore(cur ^ 1);
  }

  // epilogue: C/D layout col=lane&15, row=(lane>>4)*4+reg
  if (tensor < 2) {
    float* o = ftQK + ((size_t)(tensor * 64 + bh) * 4 + part) * 8192;
    int row0 = w * 16 + qd * 4;
#pragma unroll
    for (int nt = 0; nt < 4; ++nt) {
      int col = nt * 16 + l15;
#pragma unroll
      for (int r = 0; r < 4; ++r) o[(row0 + r) * 64 + col] = acc[nt][r];
    }
  } else {
    unsigned short* o = ftV + ((size_t)bh * 4 + part) * 8192;
    int row0 = w * 16 + qd * 4;
#pragma unroll
    for (int nt = 0; nt < 4; ++nt) {
      int col = nt * 16 + l15;
#pragma unroll
      for (int r = 0; r < 4; ++r)
        o[(row0 + r) * 64 + col] = f2bfu(acc[nt][r]);
    }
  }
}

// ---------------------------------------------------------------- attention
// grid 256 = 64 bh * 4 mq ; block 256. Sums 4 K-parts; writes ypT bf16 [bh][d][128k].
#define FST 132
__global__ __launch_bounds__(256) void attn(const float* __restrict__ ftQK,
                                            const unsigned short* __restrict__ ftV,
                                            unsigned short* __restrict__ ypt) {
  int bh = blockIdx.x >> 2, mq = blockIdx.x & 3;
  int t = threadIdx.x;

  __shared__ float qf[16 * FST];
  __shared__ float kf[64 * FST];
  __shared__ float vf[64 * FST];
  __shared__ float S[16 * FST];

  const float* qb = ftQK + (size_t)bh * 4 * 8192;
  const float* kb = ftQK + (size_t)(64 + bh) * 4 * 8192;
  const unsigned short* vb = ftV + (size_t)bh * 4 * 8192;

  // stage K (fp32 x4 parts), V (bf16 x4 parts)
#pragma unroll
  for (int j = 0; j < 8; ++j) {
    int u4 = t + 256 * j;  // < 2048
    int row = u4 >> 4, dq = u4 & 15;
    float4 ksum = make_float4(0.f, 0.f, 0.f, 0.f);
    float vsum[4] = {0.f, 0.f, 0.f, 0.f};
#pragma unroll
    for (int p = 0; p < 4; ++p) {
      float4 a = *(const float4*)&kb[(size_t)p * 8192 + row * 64 + dq * 4];
      ksum.x += a.x; ksum.y += a.y; ksum.z += a.z; ksum.w += a.w;
      ushort4 vv = *(const ushort4*)&vb[(size_t)p * 8192 + row * 64 + dq * 4];
      vsum[0] += bfu2f(vv.x); vsum[1] += bfu2f(vv.y);
      vsum[2] += bfu2f(vv.z); vsum[3] += bfu2f(vv.w);
    }
    int mm = row & 63, reim = row >> 6;
    int base = mm * FST + reim;
    kf[base + 2 * (4 * dq + 0)] = ksum.x;
    kf[base + 2 * (4 * dq + 1)] = ksum.y;
    kf[base + 2 * (4 * dq + 2)] = ksum.z;
    kf[base + 2 * (4 * dq + 3)] = ksum.w;
    vf[base + 2 * (4 * dq + 0)] = vsum[0];
    vf[base + 2 * (4 * dq + 1)] = vsum[1];
    vf[base + 2 * (4 * dq + 2)] = vsum[2];
    vf[base + 2 * (4 * dq + 3)] = vsum[3];
  }
  // stage Q rows mq*16..+15
#pragma unroll
  for (int j = 0; j < 2; ++j) {
    int u4 = t + 256 * j;  // < 512
    int rl = u4 >> 4, dq = u4 & 15;
    int i = rl & 15, reim = rl >> 4;
    int row = reim * 64 + mq * 16 + i;
    float4 qsum = make_float4(0.f, 0.f, 0.f, 0.f);
#pragma unroll
    for (int p = 0; p < 4; ++p) {
      float4 a = *(const float4*)&qb[(size_t)p * 8192 + row * 64 + dq * 4];
      qsum.x += a.x; qsum.y += a.y; qsum.z += a.z; qsum.w += a.w;
    }
    int base = i * FST + reim;
    qf[base + 2 * (4 * dq + 0)] = qsum.x;
    qf[base + 2 * (4 * dq + 1)] = qsum.y;
    qf[base + 2 * (4 * dq + 2)] = qsum.z;
    qf[base + 2 * (4 * dq + 3)] = qsum.w;
  }
  __syncthreads();

  int m = t >> 4;
  int n0 = t & 15;
#pragma unroll
  for (int nn = 0; nn < 4; ++nn) {
    int n = n0 + 16 * nn;
    float xr = 0.0f, xi = 0.0f;
    for (int d2 = 0; d2 < 32; ++d2) {
      float4 qv = *(const float4*)&qf[m * FST + 4 * d2];
      float4 kv = *(const float4*)&kf[n * FST + 4 * d2];
      xr = fmaf(qv.x, kv.x, xr); xr = fmaf(-qv.y, kv.y, xr);
      xi = fmaf(qv.x, kv.y, xi); xi = fmaf(qv.y, kv.x, xi);
      xr = fmaf(qv.z, kv.z, xr); xr = fmaf(-qv.w, kv.w, xr);
      xi = fmaf(qv.z, kv.w, xi); xi = fmaf(qv.w, kv.z, xi);
    }
    float x = xr * 0.125f, y = xi * 0.125f;
    float tr, tim;
    if (fabsf(x) > 40.0f) {
      tr = x > 0.0f ? 1.0f : -1.0f;
      tim = 0.0f;
    } else {
      float sh = sinhf(2.0f * x), ch = coshf(2.0f * x);
      float sn, cn;
      sincosf(2.0f * y, &sn, &cn);
      float den = ch + cn;
      tr = sh / den;
      tim = sn / den;
    }
    S[m * FST + 2 * n] = tr;
    S[m * FST + 2 * n + 1] = tim;
  }
  __syncthreads();

  int d0 = t & 15;
  float ar4[4] = {0, 0, 0, 0}, ai4[4] = {0, 0, 0, 0};
  for (int n = 0; n < 64; ++n) {
    float sr_ = S[m * FST + 2 * n];
    float si_ = S[m * FST + 2 * n + 1];
    float4 va = *(const float4*)&vf[n * FST + 8 * d0];
    float4 vb2 = *(const float4*)&vf[n * FST + 8 * d0 + 4];
    ar4[0] = fmaf(sr_, va.x, ar4[0]); ar4[0] = fmaf(-si_, va.y, ar4[0]);
    ai4[0] = fmaf(sr_, va.y, ai4[0]); ai4[0] = fmaf(si_, va.x, ai4[0]);
    ar4[1] = fmaf(sr_, va.z, ar4[1]); ar4[1] = fmaf(-si_, va.w, ar4[1]);
    ai4[1] = fmaf(sr_, va.w, ai4[1]); ai4[1] = fmaf(si_, va.z, ai4[1]);
    ar4[2] = fmaf(sr_, vb2.x, ar4[2]); ar4[2] = fmaf(-si_, vb2.y, ar4[2]);
    ai4[2] = fmaf(sr_, vb2.y, ai4[2]); ai4[2] = fmaf(si_, vb2.x, ai4[2]);
    ar4[3] = fmaf(sr_, vb2.z, ar4[3]); ar4[3] = fmaf(-si_, vb2.w, ar4[3]);
    ai4[3] = fmaf(sr_, vb2.w, ai4[3]); ai4[3] = fmaf(si_, vb2.z, ai4[3]);
  }
  int fbin = mq * 16 + m;
  float cf = (fbin == 0 ? 1.0f : 2.0f) / 4096.0f;
#pragma unroll
  for (int c = 0; c < 4; ++c) {
    int d = 4 * d0 + c;
    ypt[((size_t)bh * 64 + d) * 128 + 2 * fbin] = f2bfu(cf * ar4[c]);
    ypt[((size_t)bh * 64 + d) * 128 + 2 * fbin + 1] = f2bfu(cf * ai4[c]);
  }
}

// ---------------------------------------------------------------- irfft (bf16 MFMA GEMM)
// grid 4096 = 64 bh * 64 lchunk ; block 256 (4 waves). out[l][d] = sum_k btT[l][k]*ypt[d][k]
__global__ __launch_bounds__(256) void irfft_mfma(
    const unsigned short* __restrict__ ypt,
    const unsigned short* __restrict__ btT, float* __restrict__ out) {
  int bh = blockIdx.x >> 6, lc = blockIdx.x & 63;
  int t = threadIdx.x;
  int lane = t & 63, w = t >> 6;
  int l15 = lane & 15, qd = lane >> 4;

  __shared__ __align__(16) unsigned short A[2 * 64 * 72];  // [khalf][l][k64]
  __shared__ __align__(16) unsigned short Bm[2 * 64 * 72]; // [khalf][d][k64]

#pragma unroll
  for (int j = 0; j < 4; ++j) {
    int u = t + 256 * j;  // < 1024
    int row = u >> 4, seg = u & 15;
    int kh = seg >> 3, s8 = seg & 7;
    *(float4*)&A[kh * 4608 + row * 72 + s8 * 8] =
        *(const float4*)&btT[(size_t)(lc * 64 + row) * 128 + seg * 8];
    *(float4*)&Bm[kh * 4608 + row * 72 + s8 * 8] =
        *(const float4*)&ypt[(size_t)(bh * 64 + row) * 128 + seg * 8];
  }
  __syncthreads();

  f32x4 acc[4];
#pragma unroll
  for (int nt = 0; nt < 4; ++nt) acc[nt] = (f32x4){0.f, 0.f, 0.f, 0.f};

#pragma unroll
  for (int kh = 0; kh < 2; ++kh)
#pragma unroll
    for (int ks = 0; ks < 2; ++ks) {
      bf16x8 af =
          *(const bf16x8*)&A[kh * 4608 + (w * 16 + l15) * 72 + ks * 32 + qd * 8];
#pragma unroll
      for (int nt = 0; nt < 4; ++nt) {
        bf16x8 bf =
            *(const bf16x8*)&Bm[kh * 4608 + (nt * 16 + l15) * 72 + ks * 32 +
                                qd * 8];
        acc[nt] = __builtin_amdgcn_mfma_f32_16x16x32_bf16(af, bf, acc[nt], 0, 0, 0);
      }
    }

  float* obase = out + ((size_t)bh * 4096 + lc * 64) * 64;
  int row0 = w * 16 + qd * 4;
#pragma unroll
  for (int nt = 0; nt < 4; ++nt) {
    int col = nt * 16 + l15;
#pragma unroll
    for (int r = 0; r < 4; ++r) obase[(row0 + r) * 64 + col] = acc[nt][r];
  }
}

extern "C" void kernel_launch(void* const* d_in, const int* in_sizes, int n_in,
                              void* d_out, int out_size, void* d_ws,
                              size_t ws_size, hipStream_t stream) {
  const float* q = (const float*)d_in[0];
  const float* k = (const float*)d_in[1];
  const float* v = (const float*)d_in[2];
  const int* iq = (const int*)d_in[3];
  const int* ik = (const int*)d_in[4];
  const int* iv = (const int*)d_in[5];
  char* ws = (char*)d_ws;
  unsigned short* btT = (unsigned short*)ws;
  unsigned short* ypt = (unsigned short*)(ws + 1048576);
  float* ftQK = (float*)(ws + 2097152);
  unsigned short* ftV = (unsigned short*)(ws + 18874368);
  unsigned short* whi = (unsigned short*)(ws + 23068672);
  unsigned short* wlo = (unsigned short*)(ws + 26214400);
  float* out = (float*)d_out;

  hipLaunchKernelGGL(init_btT, dim3(2048), dim3(256), 0, stream, btT);
  hipLaunchKernelGGL(init_w, dim3(6144), dim3(256), 0, stream, whi, wlo, iq,
                     ik, iv);
  hipLaunchKernelGGL(dft_mfma, dim3(768), dim3(512), 0, stream, q, k, v, whi,
                     wlo, ftQK, ftV);
  hipLaunchKernelGGL(attn, dim3(256), dim3(256), 0, stream, ftQK, ftV, ypt);
  hipLaunchKernelGGL(irfft_mfma, dim3(4096), dim3(256), 0, stream, ypt, btT,
                     out);
}

// Round 3
// 260.900 us; speedup vs baseline: 1.0434x; 1.0434x over previous
//
#include <hip/hip_runtime.h>
#include <hip/hip_bf16.h>
#include <math.h>

#define LSEQ 4096
#define DIM 64
#define TWO_PI 6.28318530717958647692f

typedef __attribute__((ext_vector_type(8))) short bf16x8;
typedef __attribute__((ext_vector_type(4))) float f32x4;

// ws layout (bytes):
//   btT  bf16 [4096][128]            1,048,576 @ 0
//   ypt  bf16 [64 bh][64 d][128 k]   1,048,576 @ 1,048,576
//   ftQK fp32 [128 tbh][4][128][64] 16,777,216 @ 2,097,152
//   ftV  bf16 [64 bh][4][128][64]    4,194,304 @ 18,874,368
//   Whi  bf16 [3][128][4096]         3,145,728 @ 23,068,672
//   Wlo  bf16 [3][128][4096]         3,145,728 @ 26,214,400
//   total 29,360,128

__device__ __forceinline__ unsigned short f2bfu(float f) {
  __hip_bfloat16 h = __float2bfloat16(f);
  return *(unsigned short*)&h;
}
__device__ __forceinline__ float bfu2f(unsigned short h) {
  union { unsigned int u; float f; } z;
  z.u = ((unsigned int)h) << 16;
  return z.f;
}

// ---------------------------------------------------------------- init btT (irfft basis, bf16)
__global__ __launch_bounds__(256) void init_btT(unsigned short* __restrict__ btT) {
  int u = blockIdx.x * 256 + threadIdx.x;  // < 4096*128
  int l = u >> 7, kk = u & 127;
  int f = kk >> 1;
  float ang = (float)((f * l) & 4095) * (TWO_PI / 4096.0f);
  float s, c;
  sincosf(ang, &s, &c);
  float val = (kk & 1) ? -s : c;
  btT[u] = f2bfu(val);
}

// ---------------------------------------------------------------- init W hi/lo (DFT twiddles)
__global__ __launch_bounds__(256) void init_w(unsigned short* __restrict__ whi,
                                              unsigned short* __restrict__ wlo,
                                              const int* __restrict__ iq,
                                              const int* __restrict__ ik,
                                              const int* __restrict__ iv) {
  int u = blockIdx.x * 256 + threadIdx.x;  // < 3*128*4096
  int tensor = u >> 19;
  int rem = u & 524287;
  int row = rem >> 12;
  int l = rem & 4095;
  int m = row & 63, reim = row >> 6;
  const int* idx = (tensor == 0 ? iq : tensor == 1 ? ik : iv);
  int f = idx[m];
  float ang = (float)((f * l) & 4095) * (TWO_PI / 4096.0f);
  float s, c;
  sincosf(ang, &s, &c);
  float val = reim ? -s : c;  // e^{-i t}: re=cos, im=-sin
  __hip_bfloat16 hb = __float2bfloat16(val);
  float fh = __bfloat162float(hb);
  whi[u] = *(unsigned short*)&hb;
  wlo[u] = f2bfu(val - fh);
}

// ---------------------------------------------------------------- MFMA DFT (split-bf16)
// grid 768 = 3 tensor * 64 bh * 4 Kpart ; block 512 (8 waves, 1 M-tile/wave)
// v4: raw-barrier pipeline. __syncthreads() forces vmcnt(0) before s_barrier,
//     which drained the X prefetch every chunk (R0-R2 all pinned ~95us).
//     Replace with lgkmcnt(0)+s_barrier+sched_barrier(0): W/X register loads
//     stay in flight across the barrier; MFMA waits a counted vmcnt (W only).
__global__ __launch_bounds__(512, 4) void dft_mfma(
    const float* __restrict__ q, const float* __restrict__ k,
    const float* __restrict__ v, const unsigned short* __restrict__ whi,
    const unsigned short* __restrict__ wlo, float* __restrict__ ftQK,
    unsigned short* __restrict__ ftV) {
  int b = blockIdx.x;
  int tensor = b >> 8;
  int bh = (b >> 2) & 63;
  int part = b & 3;
  const float* x =
      (tensor == 0 ? q : tensor == 1 ? k : v) + (size_t)bh * (LSEQ * DIM);
  const unsigned short* wh = whi + (size_t)tensor * 524288;
  const unsigned short* wl = wlo + (size_t)tensor * 524288;

  int t = threadIdx.x;
  int lane = t & 63, w = t >> 6;           // w 0..7 -> M rows w*16..w*16+15
  int l15 = lane & 15, qd = lane >> 4;
  int xd = t & 63, xseg = t >> 6;          // 8 X rows per thread

  __shared__ __align__(16) unsigned short Xh[2][64 * 72];
  __shared__ __align__(16) unsigned short Xl[2][64 * 72];

  f32x4 acc[4];
#pragma unroll
  for (int nt = 0; nt < 4; ++nt) acc[nt] = (f32x4){0.f, 0.f, 0.f, 0.f};

  bool split = (tensor != 2);
  int k0 = part * 1024;

  // per-lane W fragment base: row = w*16 + l15, col qd*8 (+lc+ks*32)
  const unsigned short* wrh = wh + (size_t)(w * 16 + l15) * 4096 + qd * 8;
  const unsigned short* wrl = wl + (size_t)(w * 16 + l15) * 4096 + qd * 8;

  float xv[8];

  // convert xv -> hi/lo bf16 and store to buffer `buf`
  auto cvstore = [&](int buf) {
    __align__(16) unsigned short hs[8];
    __align__(16) unsigned short ls[8];
#pragma unroll
    for (int i = 0; i < 8; ++i) {
      __hip_bfloat16 hb = __float2bfloat16(xv[i]);
      hs[i] = *(unsigned short*)&hb;
      float fh = __bfloat162float(hb);
      ls[i] = f2bfu(xv[i] - fh);
    }
    *(bf16x8*)&Xh[buf][xd * 72 + xseg * 8] = *(bf16x8*)&hs[0];
    *(bf16x8*)&Xl[buf][xd * 72 + xseg * 8] = *(bf16x8*)&ls[0];
  };

  // prologue: chunk 0 -> buf 0
  {
    const float* xp = x + (size_t)(k0 + xseg * 8) * 64 + xd;
#pragma unroll
    for (int i = 0; i < 8; ++i) xv[i] = xp[(size_t)i * 64];
  }
  cvstore(0);

  for (int ch = 0; ch < 16; ++ch) {
    int lc = k0 + ch * 64;
    int cur = ch & 1;

    // Raw barrier: drain only LDS (my ds_writes of buf[cur] from prev iter /
    // prologue, and my ds_reads of the buffer iter ch+1 will overwrite).
    // Register-destined vmem (W, X prefetch) legally stays in flight.
    asm volatile("s_waitcnt lgkmcnt(0)" ::: "memory");
    __builtin_amdgcn_s_barrier();
    __builtin_amdgcn_sched_barrier(0);

    // W fragments for THIS chunk: issued first => the MFMA dependence wait is
    // a counted vmcnt leaving the newer X prefetch in flight.
    bf16x8 afh[2], afl[2];
#pragma unroll
    for (int ks = 0; ks < 2; ++ks)
      afh[ks] = *(const bf16x8*)(wrh + lc + ks * 32);
    if (split) {
#pragma unroll
      for (int ks = 0; ks < 2; ++ks)
        afl[ks] = *(const bf16x8*)(wrl + lc + ks * 32);
    }

    // X prefetch for NEXT chunk (HBM latency hides under the MFMA section)
    if (ch < 15) {
      const float* xp = x + (size_t)(lc + 64 + xseg * 8) * 64 + xd;
#pragma unroll
      for (int i = 0; i < 8; ++i) xv[i] = xp[(size_t)i * 64];
    }

    if (split) {
#pragma unroll
      for (int ks = 0; ks < 2; ++ks) {
        bf16x8 bh_[4], bl_[4];
#pragma unroll
        for (int nt = 0; nt < 4; ++nt) {
          bh_[nt] =
              *(const bf16x8*)&Xh[cur][(nt * 16 + l15) * 72 + ks * 32 + qd * 8];
          bl_[nt] =
              *(const bf16x8*)&Xl[cur][(nt * 16 + l15) * 72 + ks * 32 + qd * 8];
        }
#pragma unroll
        for (int nt = 0; nt < 4; ++nt) {
          acc[nt] = __builtin_amdgcn_mfma_f32_16x16x32_bf16(
              afh[ks], bh_[nt], acc[nt], 0, 0, 0);
          acc[nt] = __builtin_amdgcn_mfma_f32_16x16x32_bf16(
              afh[ks], bl_[nt], acc[nt], 0, 0, 0);
          acc[nt] = __builtin_amdgcn_mfma_f32_16x16x32_bf16(
              afl[ks], bh_[nt], acc[nt], 0, 0, 0);
        }
      }
    } else {
#pragma unroll
      for (int ks = 0; ks < 2; ++ks) {
        bf16x8 bh_[4], bl_[4];
#pragma unroll
        for (int nt = 0; nt < 4; ++nt) {
          bh_[nt] =
              *(const bf16x8*)&Xh[cur][(nt * 16 + l15) * 72 + ks * 32 + qd * 8];
          bl_[nt] =
              *(const bf16x8*)&Xl[cur][(nt * 16 + l15) * 72 + ks * 32 + qd * 8];
        }
#pragma unroll
        for (int nt = 0; nt < 4; ++nt) {
          acc[nt] = __builtin_amdgcn_mfma_f32_16x16x32_bf16(
              afh[ks], bh_[nt], acc[nt], 0, 0, 0);
          acc[nt] = __builtin_amdgcn_mfma_f32_16x16x32_bf16(
              afh[ks], bl_[nt], acc[nt], 0, 0, 0);
        }
      }
    }

    // convert + write next chunk into the other buffer (compiler inserts the
    // vmcnt wait for the X regs here, after the MFMAs). Reads of buf[cur^1]
    // by other waves finished before the barrier above.
    if (ch < 15) cvstore(cur ^ 1);
  }

  // epilogue: C/D layout col=lane&15, row=(lane>>4)*4+reg
  if (tensor < 2) {
    float* o = ftQK + ((size_t)(tensor * 64 + bh) * 4 + part) * 8192;
    int row0 = w * 16 + qd * 4;
#pragma unroll
    for (int nt = 0; nt < 4; ++nt) {
      int col = nt * 16 + l15;
#pragma unroll
      for (int r = 0; r < 4; ++r) o[(row0 + r) * 64 + col] = acc[nt][r];
    }
  } else {
    unsigned short* o = ftV + ((size_t)bh * 4 + part) * 8192;
    int row0 = w * 16 + qd * 4;
#pragma unroll
    for (int nt = 0; nt < 4; ++nt) {
      int col = nt * 16 + l15;
#pragma unroll
      for (int r = 0; r < 4; ++r)
        o[(row0 + r) * 64 + col] = f2bfu(acc[nt][r]);
    }
  }
}

// ---------------------------------------------------------------- attention
// grid 256 = 64 bh * 4 mq ; block 256. Sums 4 K-parts; writes ypT bf16 [bh][d][128k].
#define FST 132
__global__ __launch_bounds__(256) void attn(const float* __restrict__ ftQK,
                                            const unsigned short* __restrict__ ftV,
                                            unsigned short* __restrict__ ypt) {
  int bh = blockIdx.x >> 2, mq = blockIdx.x & 3;
  int t = threadIdx.x;

  __shared__ float qf[16 * FST];
  __shared__ float kf[64 * FST];
  __shared__ float vf[64 * FST];
  __shared__ float S[16 * FST];

  const float* qb = ftQK + (size_t)bh * 4 * 8192;
  const float* kb = ftQK + (size_t)(64 + bh) * 4 * 8192;
  const unsigned short* vb = ftV + (size_t)bh * 4 * 8192;

  // stage K (fp32 x4 parts), V (bf16 x4 parts)
#pragma unroll
  for (int j = 0; j < 8; ++j) {
    int u4 = t + 256 * j;  // < 2048
    int row = u4 >> 4, dq = u4 & 15;
    float4 ksum = make_float4(0.f, 0.f, 0.f, 0.f);
    float vsum[4] = {0.f, 0.f, 0.f, 0.f};
#pragma unroll
    for (int p = 0; p < 4; ++p) {
      float4 a = *(const float4*)&kb[(size_t)p * 8192 + row * 64 + dq * 4];
      ksum.x += a.x; ksum.y += a.y; ksum.z += a.z; ksum.w += a.w;
      ushort4 vv = *(const ushort4*)&vb[(size_t)p * 8192 + row * 64 + dq * 4];
      vsum[0] += bfu2f(vv.x); vsum[1] += bfu2f(vv.y);
      vsum[2] += bfu2f(vv.z); vsum[3] += bfu2f(vv.w);
    }
    int mm = row & 63, reim = row >> 6;
    int base = mm * FST + reim;
    kf[base + 2 * (4 * dq + 0)] = ksum.x;
    kf[base + 2 * (4 * dq + 1)] = ksum.y;
    kf[base + 2 * (4 * dq + 2)] = ksum.z;
    kf[base + 2 * (4 * dq + 3)] = ksum.w;
    vf[base + 2 * (4 * dq + 0)] = vsum[0];
    vf[base + 2 * (4 * dq + 1)] = vsum[1];
    vf[base + 2 * (4 * dq + 2)] = vsum[2];
    vf[base + 2 * (4 * dq + 3)] = vsum[3];
  }
  // stage Q rows mq*16..+15
#pragma unroll
  for (int j = 0; j < 2; ++j) {
    int u4 = t + 256 * j;  // < 512
    int rl = u4 >> 4, dq = u4 & 15;
    int i = rl & 15, reim = rl >> 4;
    int row = reim * 64 + mq * 16 + i;
    float4 qsum = make_float4(0.f, 0.f, 0.f, 0.f);
#pragma unroll
    for (int p = 0; p < 4; ++p) {
      float4 a = *(const float4*)&qb[(size_t)p * 8192 + row * 64 + dq * 4];
      qsum.x += a.x; qsum.y += a.y; qsum.z += a.z; qsum.w += a.w;
    }
    int base = i * FST + reim;
    qf[base + 2 * (4 * dq + 0)] = qsum.x;
    qf[base + 2 * (4 * dq + 1)] = qsum.y;
    qf[base + 2 * (4 * dq + 2)] = qsum.z;
    qf[base + 2 * (4 * dq + 3)] = qsum.w;
  }
  __syncthreads();

  int m = t >> 4;
  int n0 = t & 15;
#pragma unroll
  for (int nn = 0; nn < 4; ++nn) {
    int n = n0 + 16 * nn;
    float xr = 0.0f, xi = 0.0f;
    for (int d2 = 0; d2 < 32; ++d2) {
      float4 qv = *(const float4*)&qf[m * FST + 4 * d2];
      float4 kv = *(const float4*)&kf[n * FST + 4 * d2];
      xr = fmaf(qv.x, kv.x, xr); xr = fmaf(-qv.y, kv.y, xr);
      xi = fmaf(qv.x, kv.y, xi); xi = fmaf(qv.y, kv.x, xi);
      xr = fmaf(qv.z, kv.z, xr); xr = fmaf(-qv.w, kv.w, xr);
      xi = fmaf(qv.z, kv.w, xi); xi = fmaf(qv.w, kv.z, xi);
    }
    float x = xr * 0.125f, y = xi * 0.125f;
    float tr, tim;
    if (fabsf(x) > 40.0f) {
      tr = x > 0.0f ? 1.0f : -1.0f;
      tim = 0.0f;
    } else {
      float sh = sinhf(2.0f * x), ch = coshf(2.0f * x);
      float sn, cn;
      sincosf(2.0f * y, &sn, &cn);
      float den = ch + cn;
      tr = sh / den;
      tim = sn / den;
    }
    S[m * FST + 2 * n] = tr;
    S[m * FST + 2 * n + 1] = tim;
  }
  __syncthreads();

  int d0 = t & 15;
  float ar4[4] = {0, 0, 0, 0}, ai4[4] = {0, 0, 0, 0};
  for (int n = 0; n < 64; ++n) {
    float sr_ = S[m * FST + 2 * n];
    float si_ = S[m * FST + 2 * n + 1];
    float4 va = *(const float4*)&vf[n * FST + 8 * d0];
    float4 vb2 = *(const float4*)&vf[n * FST + 8 * d0 + 4];
    ar4[0] = fmaf(sr_, va.x, ar4[0]); ar4[0] = fmaf(-si_, va.y, ar4[0]);
    ai4[0] = fmaf(sr_, va.y, ai4[0]); ai4[0] = fmaf(si_, va.x, ai4[0]);
    ar4[1] = fmaf(sr_, va.z, ar4[1]); ar4[1] = fmaf(-si_, va.w, ar4[1]);
    ai4[1] = fmaf(sr_, va.w, ai4[1]); ai4[1] = fmaf(si_, va.z, ai4[1]);
    ar4[2] = fmaf(sr_, vb2.x, ar4[2]); ar4[2] = fmaf(-si_, vb2.y, ar4[2]);
    ai4[2] = fmaf(sr_, vb2.y, ai4[2]); ai4[2] = fmaf(si_, vb2.x, ai4[2]);
    ar4[3] = fmaf(sr_, vb2.z, ar4[3]); ar4[3] = fmaf(-si_, vb2.w, ar4[3]);
    ai4[3] = fmaf(sr_, vb2.w, ai4[3]); ai4[3] = fmaf(si_, vb2.z, ai4[3]);
  }
  int fbin = mq * 16 + m;
  float cf = (fbin == 0 ? 1.0f : 2.0f) / 4096.0f;
#pragma unroll
  for (int c = 0; c < 4; ++c) {
    int d = 4 * d0 + c;
    ypt[((size_t)bh * 64 + d) * 128 + 2 * fbin] = f2bfu(cf * ar4[c]);
    ypt[((size_t)bh * 64 + d) * 128 + 2 * fbin + 1] = f2bfu(cf * ai4[c]);
  }
}

// ---------------------------------------------------------------- irfft (bf16 MFMA GEMM)
// grid 4096 = 64 bh * 64 lchunk ; block 256 (4 waves). out[l][d] = sum_k btT[l][k]*ypt[d][k]
__global__ __launch_bounds__(256) void irfft_mfma(
    const unsigned short* __restrict__ ypt,
    const unsigned short* __restrict__ btT, float* __restrict__ out) {
  int bh = blockIdx.x >> 6, lc = blockIdx.x & 63;
  int t = threadIdx.x;
  int lane = t & 63, w = t >> 6;
  int l15 = lane & 15, qd = lane >> 4;

  __shared__ __align__(16) unsigned short A[2 * 64 * 72];  // [khalf][l][k64]
  __shared__ __align__(16) unsigned short Bm[2 * 64 * 72]; // [khalf][d][k64]

#pragma unroll
  for (int j = 0; j < 4; ++j) {
    int u = t + 256 * j;  // < 1024
    int row = u >> 4, seg = u & 15;
    int kh = seg >> 3, s8 = seg & 7;
    *(float4*)&A[kh * 4608 + row * 72 + s8 * 8] =
        *(const float4*)&btT[(size_t)(lc * 64 + row) * 128 + seg * 8];
    *(float4*)&Bm[kh * 4608 + row * 72 + s8 * 8] =
        *(const float4*)&ypt[(size_t)(bh * 64 + row) * 128 + seg * 8];
  }
  __syncthreads();

  f32x4 acc[4];
#pragma unroll
  for (int nt = 0; nt < 4; ++nt) acc[nt] = (f32x4){0.f, 0.f, 0.f, 0.f};

#pragma unroll
  for (int kh = 0; kh < 2; ++kh)
#pragma unroll
    for (int ks = 0; ks < 2; ++ks) {
      bf16x8 af =
          *(const bf16x8*)&A[kh * 4608 + (w * 16 + l15) * 72 + ks * 32 + qd * 8];
#pragma unroll
      for (int nt = 0; nt < 4; ++nt) {
        bf16x8 bf =
            *(const bf16x8*)&Bm[kh * 4608 + (nt * 16 + l15) * 72 + ks * 32 +
                                qd * 8];
        acc[nt] = __builtin_amdgcn_mfma_f32_16x16x32_bf16(af, bf, acc[nt], 0, 0, 0);
      }
    }

  float* obase = out + ((size_t)bh * 4096 + lc * 64) * 64;
  int row0 = w * 16 + qd * 4;
#pragma unroll
  for (int nt = 0; nt < 4; ++nt) {
    int col = nt * 16 + l15;
#pragma unroll
    for (int r = 0; r < 4; ++r) obase[(row0 + r) * 64 + col] = acc[nt][r];
  }
}

extern "C" void kernel_launch(void* const* d_in, const int* in_sizes, int n_in,
                              void* d_out, int out_size, void* d_ws,
                              size_t ws_size, hipStream_t stream) {
  const float* q = (const float*)d_in[0];
  const float* k = (const float*)d_in[1];
  const float* v = (const float*)d_in[2];
  const int* iq = (const int*)d_in[3];
  const int* ik = (const int*)d_in[4];
  const int* iv = (const int*)d_in[5];
  char* ws = (char*)d_ws;
  unsigned short* btT = (unsigned short*)ws;
  unsigned short* ypt = (unsigned short*)(ws + 1048576);
  float* ftQK = (float*)(ws + 2097152);
  unsigned short* ftV = (unsigned short*)(ws + 18874368);
  unsigned short* whi = (unsigned short*)(ws + 23068672);
  unsigned short* wlo = (unsigned short*)(ws + 26214400);
  float* out = (float*)d_out;

  hipLaunchKernelGGL(init_btT, dim3(2048), dim3(256), 0, stream, btT);
  hipLaunchKernelGGL(init_w, dim3(6144), dim3(256), 0, stream, whi, wlo, iq,
                     ik, iv);
  hipLaunchKernelGGL(dft_mfma, dim3(768), dim3(512), 0, stream, q, k, v, whi,
                     wlo, ftQK, ftV);
  hipLaunchKernelGGL(attn, dim3(256), dim3(256), 0, stream, ftQK, ftV, ypt);
  hipLaunchKernelGGL(irfft_mfma, dim3(4096), dim3(256), 0, stream, ypt, btT,
                     out);
}

// Round 4
// 255.920 us; speedup vs baseline: 1.0638x; 1.0195x over previous
//
#include <hip/hip_runtime.h>
#include <hip/hip_bf16.h>
#include <math.h>

#define LSEQ 4096
#define DIM 64
#define TWO_PI 6.28318530717958647692f

typedef __attribute__((ext_vector_type(8))) short bf16x8;
typedef __attribute__((ext_vector_type(4))) float f32x4;

// ws layout (bytes):
//   btT  bf16 [4096][128]            1,048,576 @ 0
//   ypt  bf16 [64 bh][64 d][128 k]   1,048,576 @ 1,048,576
//   ftQK fp32 [128 tbh][4][128][64] 16,777,216 @ 2,097,152
//   ftV  bf16 [64 bh][4][128][64]    4,194,304 @ 18,874,368
//   Whi  bf16 [3][128 panels][128 rows][32 k] (swizzled panel image) @ 23,068,672
//   Wlo  bf16 same layout                                            @ 26,214,400
//   total 29,360,128

__device__ __forceinline__ unsigned short f2bfu(float f) {
  __hip_bfloat16 h = __float2bfloat16(f);
  return *(unsigned short*)&h;
}
__device__ __forceinline__ float bfu2f(unsigned short h) {
  union { unsigned int u; float f; } z;
  z.u = ((unsigned int)h) << 16;
  return z.f;
}

// async global->LDS 16B DMA (coalesced, no VGPR round trip)
#define GLOAD16(gsrc, ldst)                                              \
  __builtin_amdgcn_global_load_lds(                                      \
      (const __attribute__((address_space(1))) void*)(gsrc),             \
      (__attribute__((address_space(3))) void*)(ldst), 16, 0, 0)

// ---------------------------------------------------------------- init btT (irfft basis, bf16)
__global__ __launch_bounds__(256) void init_btT(unsigned short* __restrict__ btT) {
  int u = blockIdx.x * 256 + threadIdx.x;  // < 4096*128
  int l = u >> 7, kk = u & 127;
  int f = kk >> 1;
  float ang = (float)((f * l) & 4095) * (TWO_PI / 4096.0f);
  float s, c;
  sincosf(ang, &s, &c);
  float val = (kk & 1) ? -s : c;
  btT[u] = f2bfu(val);
}

// ---------------------------------------------------------------- init W hi/lo (DFT twiddles)
// v5: writes W as 8KB K32-panels in the EXACT (swizzled) LDS image dft wants:
//   panel p = l>>5 ; within panel: row*32 + ((seg ^ (row&3))*8) + (kc&7),
//   seg = (l&31)>>3. 16B-seg XOR swizzle kills ds_read_b128 bank conflicts.
__global__ __launch_bounds__(256) void init_w(unsigned short* __restrict__ whi,
                                              unsigned short* __restrict__ wlo,
                                              const int* __restrict__ iq,
                                              const int* __restrict__ ik,
                                              const int* __restrict__ iv) {
  int u = blockIdx.x * 256 + threadIdx.x;  // < 3*128*4096
  int tensor = u >> 19;
  int rem = u & 524287;
  int row = rem >> 12;
  int l = rem & 4095;
  int m = row & 63, reim = row >> 6;
  const int* idx = (tensor == 0 ? iq : tensor == 1 ? ik : iv);
  int f = idx[m];
  float ang = (float)((f * l) & 4095) * (TWO_PI / 4096.0f);
  float s, c;
  sincosf(ang, &s, &c);
  float val = reim ? -s : c;  // e^{-i t}: re=cos, im=-sin
  __hip_bfloat16 hb = __float2bfloat16(val);
  float fh = __bfloat162float(hb);
  int panel = l >> 5, kc = l & 31, seg = kc >> 3;
  int o = (tensor << 19) + (panel << 12) + (row << 5) +
          (((seg ^ (row & 3)) << 3) | (kc & 7));
  whi[o] = *(unsigned short*)&hb;
  wlo[o] = f2bfu(val - fh);
}

// ---------------------------------------------------------------- MFMA DFT (split-bf16)
// grid 768 = 3 tensor * 64 bh * 4 Kpart ; block 256 (4 waves, mt=2 M-tiles/wave)
// v5: W staged via global_load_lds from pre-swizzled panels (R1/R3's per-lane
//     W gather was ~64 TA sectors/instr = the hidden ~40us serializer).
//     K32 chunks; W-DMA 1 ahead, X reg-prefetch 2 ahead; raw barrier with
//     counted vmcnt(8) keeps X in flight; sched_barrier pins W-before-X issue.
__global__ __launch_bounds__(256) void dft_mfma(
    const float* __restrict__ q, const float* __restrict__ k,
    const float* __restrict__ v, const unsigned short* __restrict__ whi,
    const unsigned short* __restrict__ wlo, float* __restrict__ ftQK,
    unsigned short* __restrict__ ftV) {
  int b = blockIdx.x;
  int tensor = b >> 8;
  int bh = (b >> 2) & 63;
  int part = b & 3;
  const float* x =
      (tensor == 0 ? q : tensor == 1 ? k : v) + (size_t)bh * (LSEQ * DIM);
  const unsigned short* wph = whi + (size_t)(tensor * 128 + part * 32) * 4096;
  const unsigned short* wpl = wlo + (size_t)(tensor * 128 + part * 32) * 4096;

  int t = threadIdx.x;
  int lane = t & 63, w = t >> 6;  // 4 waves, wave w owns M rows (w*2+mt)*16..
  int l15 = lane & 15, qd = lane >> 4;
  int xd = t & 63, xseg = t >> 6;  // X: thread covers d=xd, k=xseg*8..+7

  __shared__ __align__(16) unsigned short Wh[2][4096];   // [buf][row*32+swz k]
  __shared__ __align__(16) unsigned short Wl[2][4096];
  __shared__ __align__(16) unsigned short Xh[2][64 * 40];  // [buf][d][k32 pad40]
  __shared__ __align__(16) unsigned short Xl[2][64 * 40];

  f32x4 acc[2][4];
#pragma unroll
  for (int mt = 0; mt < 2; ++mt)
#pragma unroll
    for (int nt = 0; nt < 4; ++nt) acc[mt][nt] = (f32x4){0.f, 0.f, 0.f, 0.f};

  bool split = (tensor != 2);
  int k0 = part * 1024;

  float xvA[8], xvB[8];

  auto cvstore = [&](int buf, float (&xv)[8]) {
    __align__(16) unsigned short hs[8];
    __align__(16) unsigned short ls[8];
#pragma unroll
    for (int i = 0; i < 8; ++i) {
      __hip_bfloat16 hb = __float2bfloat16(xv[i]);
      hs[i] = *(unsigned short*)&hb;
      float fh = __bfloat162float(hb);
      ls[i] = f2bfu(xv[i] - fh);
    }
    *(bf16x8*)&Xh[buf][xd * 40 + xseg * 8] = *(bf16x8*)&hs[0];
    *(bf16x8*)&Xl[buf][xd * 40 + xseg * 8] = *(bf16x8*)&ls[0];
  };

  // ---- prologue: W[0] DMA -> buf0 ; X[0] -> cvstore buf0 ; X[1] -> regs
  {
    GLOAD16(wph + t * 8, &Wh[0][t * 8]);
    GLOAD16(wph + 2048 + t * 8, &Wh[0][t * 8 + 2048]);
    if (split) {
      GLOAD16(wpl + t * 8, &Wl[0][t * 8]);
      GLOAD16(wpl + 2048 + t * 8, &Wl[0][t * 8 + 2048]);
    }
    __builtin_amdgcn_sched_barrier(0);
    const float* xp = x + (size_t)(k0 + xseg * 8) * 64 + xd;
#pragma unroll
    for (int i = 0; i < 8; ++i) xvA[i] = xp[(size_t)i * 64];
    cvstore(0, xvA);
    const float* xp1 = x + (size_t)(k0 + 32 + xseg * 8) * 64 + xd;
#pragma unroll
    for (int i = 0; i < 8; ++i) xvB[i] = xp1[(size_t)i * 64];
  }

  auto body = [&](int ch, int cur, float (&xvLoad)[8], float (&xvUse)[8]) {
    // counted wait: drains my ds ops + the W DMA (oldest), leaves the 8
    // newer X reg-loads in flight across the barrier.
    if (ch == 31)
      asm volatile("s_waitcnt lgkmcnt(0) vmcnt(0)" ::: "memory");
    else
      asm volatile("s_waitcnt lgkmcnt(0) vmcnt(8)" ::: "memory");
    __builtin_amdgcn_s_barrier();
    __builtin_amdgcn_sched_barrier(0);

    // W[ch+1] DMA into the other buffer (its readers finished last iter)
    if (ch < 31) {
      const unsigned short* ph = wph + (size_t)(ch + 1) * 4096 + t * 8;
      GLOAD16(ph, &Wh[cur ^ 1][t * 8]);
      GLOAD16(ph + 2048, &Wh[cur ^ 1][t * 8 + 2048]);
      if (split) {
        const unsigned short* pl = wpl + (size_t)(ch + 1) * 4096 + t * 8;
        GLOAD16(pl, &Wl[cur ^ 1][t * 8]);
        GLOAD16(pl + 2048, &Wl[cur ^ 1][t * 8 + 2048]);
      }
      __builtin_amdgcn_sched_barrier(0);  // keep W DMA older than X loads
    }

    // X[ch+2] -> registers (2-chunk-deep; HBM latency fully covered)
    if (ch < 30) {
      const float* xp =
          x + (size_t)(k0 + (ch + 2) * 32 + xseg * 8) * 64 + xd;
#pragma unroll
      for (int i = 0; i < 8; ++i) xvLoad[i] = xp[(size_t)i * 64];
    }

    // fragments from LDS + MFMA (K=32 -> one MFMA-K step)
    bf16x8 ah[2], al[2], bh_[4], bl_[4];
#pragma unroll
    for (int mt = 0; mt < 2; ++mt) {
      int row = (w * 2 + mt) * 16 + l15;
      ah[mt] = *(const bf16x8*)&Wh[cur][row * 32 + ((qd ^ (l15 & 3)) << 3)];
    }
    if (split) {
#pragma unroll
      for (int mt = 0; mt < 2; ++mt) {
        int row = (w * 2 + mt) * 16 + l15;
        al[mt] = *(const bf16x8*)&Wl[cur][row * 32 + ((qd ^ (l15 & 3)) << 3)];
      }
    }
#pragma unroll
    for (int nt = 0; nt < 4; ++nt) {
      bh_[nt] = *(const bf16x8*)&Xh[cur][(nt * 16 + l15) * 40 + qd * 8];
      bl_[nt] = *(const bf16x8*)&Xl[cur][(nt * 16 + l15) * 40 + qd * 8];
    }
    if (split) {
#pragma unroll
      for (int mt = 0; mt < 2; ++mt)
#pragma unroll
        for (int nt = 0; nt < 4; ++nt) {
          acc[mt][nt] = __builtin_amdgcn_mfma_f32_16x16x32_bf16(
              ah[mt], bh_[nt], acc[mt][nt], 0, 0, 0);
          acc[mt][nt] = __builtin_amdgcn_mfma_f32_16x16x32_bf16(
              ah[mt], bl_[nt], acc[mt][nt], 0, 0, 0);
          acc[mt][nt] = __builtin_amdgcn_mfma_f32_16x16x32_bf16(
              al[mt], bh_[nt], acc[mt][nt], 0, 0, 0);
        }
    } else {
#pragma unroll
      for (int mt = 0; mt < 2; ++mt)
#pragma unroll
        for (int nt = 0; nt < 4; ++nt) {
          acc[mt][nt] = __builtin_amdgcn_mfma_f32_16x16x32_bf16(
              ah[mt], bh_[nt], acc[mt][nt], 0, 0, 0);
          acc[mt][nt] = __builtin_amdgcn_mfma_f32_16x16x32_bf16(
              ah[mt], bl_[nt], acc[mt][nt], 0, 0, 0);
        }
    }

    // convert + write X[ch+1] into the other buffer (read side protected by
    // the barrier at the top of iter ch+1)
    if (ch < 31) cvstore(cur ^ 1, xvUse);
  };

#pragma unroll 1
  for (int cc = 0; cc < 16; ++cc) {
    body(2 * cc, 0, xvA, xvB);
    body(2 * cc + 1, 1, xvB, xvA);
  }

  // epilogue: C/D layout col=lane&15, row=(lane>>4)*4+reg
  if (tensor < 2) {
    float* o = ftQK + ((size_t)(tensor * 64 + bh) * 4 + part) * 8192;
#pragma unroll
    for (int mt = 0; mt < 2; ++mt) {
      int row0 = (w * 2 + mt) * 16 + qd * 4;
#pragma unroll
      for (int nt = 0; nt < 4; ++nt) {
        int col = nt * 16 + l15;
#pragma unroll
        for (int r = 0; r < 4; ++r) o[(row0 + r) * 64 + col] = acc[mt][nt][r];
      }
    }
  } else {
    unsigned short* o = ftV + ((size_t)bh * 4 + part) * 8192;
#pragma unroll
    for (int mt = 0; mt < 2; ++mt) {
      int row0 = (w * 2 + mt) * 16 + qd * 4;
#pragma unroll
      for (int nt = 0; nt < 4; ++nt) {
        int col = nt * 16 + l15;
#pragma unroll
        for (int r = 0; r < 4; ++r)
          o[(row0 + r) * 64 + col] = f2bfu(acc[mt][nt][r]);
      }
    }
  }
}

// ---------------------------------------------------------------- attention
// grid 256 = 64 bh * 4 mq ; block 256. Sums 4 K-parts; writes ypT bf16 [bh][d][128k].
#define FST 132
__global__ __launch_bounds__(256) void attn(const float* __restrict__ ftQK,
                                            const unsigned short* __restrict__ ftV,
                                            unsigned short* __restrict__ ypt) {
  int bh = blockIdx.x >> 2, mq = blockIdx.x & 3;
  int t = threadIdx.x;

  __shared__ float qf[16 * FST];
  __shared__ float kf[64 * FST];
  __shared__ float vf[64 * FST];
  __shared__ float S[16 * FST];

  const float* qb = ftQK + (size_t)bh * 4 * 8192;
  const float* kb = ftQK + (size_t)(64 + bh) * 4 * 8192;
  const unsigned short* vb = ftV + (size_t)bh * 4 * 8192;

  // stage K (fp32 x4 parts), V (bf16 x4 parts)
#pragma unroll
  for (int j = 0; j < 8; ++j) {
    int u4 = t + 256 * j;  // < 2048
    int row = u4 >> 4, dq = u4 & 15;
    float4 ksum = make_float4(0.f, 0.f, 0.f, 0.f);
    float vsum[4] = {0.f, 0.f, 0.f, 0.f};
#pragma unroll
    for (int p = 0; p < 4; ++p) {
      float4 a = *(const float4*)&kb[(size_t)p * 8192 + row * 64 + dq * 4];
      ksum.x += a.x; ksum.y += a.y; ksum.z += a.z; ksum.w += a.w;
      ushort4 vv = *(const ushort4*)&vb[(size_t)p * 8192 + row * 64 + dq * 4];
      vsum[0] += bfu2f(vv.x); vsum[1] += bfu2f(vv.y);
      vsum[2] += bfu2f(vv.z); vsum[3] += bfu2f(vv.w);
    }
    int mm = row & 63, reim = row >> 6;
    int base = mm * FST + reim;
    kf[base + 2 * (4 * dq + 0)] = ksum.x;
    kf[base + 2 * (4 * dq + 1)] = ksum.y;
    kf[base + 2 * (4 * dq + 2)] = ksum.z;
    kf[base + 2 * (4 * dq + 3)] = ksum.w;
    vf[base + 2 * (4 * dq + 0)] = vsum[0];
    vf[base + 2 * (4 * dq + 1)] = vsum[1];
    vf[base + 2 * (4 * dq + 2)] = vsum[2];
    vf[base + 2 * (4 * dq + 3)] = vsum[3];
  }
  // stage Q rows mq*16..+15
#pragma unroll
  for (int j = 0; j < 2; ++j) {
    int u4 = t + 256 * j;  // < 512
    int rl = u4 >> 4, dq = u4 & 15;
    int i = rl & 15, reim = rl >> 4;
    int row = reim * 64 + mq * 16 + i;
    float4 qsum = make_float4(0.f, 0.f, 0.f, 0.f);
#pragma unroll
    for (int p = 0; p < 4; ++p) {
      float4 a = *(const float4*)&qb[(size_t)p * 8192 + row * 64 + dq * 4];
      qsum.x += a.x; qsum.y += a.y; qsum.z += a.z; qsum.w += a.w;
    }
    int base = i * FST + reim;
    qf[base + 2 * (4 * dq + 0)] = qsum.x;
    qf[base + 2 * (4 * dq + 1)] = qsum.y;
    qf[base + 2 * (4 * dq + 2)] = qsum.z;
    qf[base + 2 * (4 * dq + 3)] = qsum.w;
  }
  __syncthreads();

  int m = t >> 4;
  int n0 = t & 15;
#pragma unroll
  for (int nn = 0; nn < 4; ++nn) {
    int n = n0 + 16 * nn;
    float xr = 0.0f, xi = 0.0f;
    for (int d2 = 0; d2 < 32; ++d2) {
      float4 qv = *(const float4*)&qf[m * FST + 4 * d2];
      float4 kv = *(const float4*)&kf[n * FST + 4 * d2];
      xr = fmaf(qv.x, kv.x, xr); xr = fmaf(-qv.y, kv.y, xr);
      xi = fmaf(qv.x, kv.y, xi); xi = fmaf(qv.y, kv.x, xi);
      xr = fmaf(qv.z, kv.z, xr); xr = fmaf(-qv.w, kv.w, xr);
      xi = fmaf(qv.z, kv.w, xi); xi = fmaf(qv.w, kv.z, xi);
    }
    float x = xr * 0.125f, y = xi * 0.125f;
    float tr, tim;
    if (fabsf(x) > 40.0f) {
      tr = x > 0.0f ? 1.0f : -1.0f;
      tim = 0.0f;
    } else {
      float sh = sinhf(2.0f * x), ch = coshf(2.0f * x);
      float sn, cn;
      sincosf(2.0f * y, &sn, &cn);
      float den = ch + cn;
      tr = sh / den;
      tim = sn / den;
    }
    S[m * FST + 2 * n] = tr;
    S[m * FST + 2 * n + 1] = tim;
  }
  __syncthreads();

  int d0 = t & 15;
  float ar4[4] = {0, 0, 0, 0}, ai4[4] = {0, 0, 0, 0};
  for (int n = 0; n < 64; ++n) {
    float sr_ = S[m * FST + 2 * n];
    float si_ = S[m * FST + 2 * n + 1];
    float4 va = *(const float4*)&vf[n * FST + 8 * d0];
    float4 vb2 = *(const float4*)&vf[n * FST + 8 * d0 + 4];
    ar4[0] = fmaf(sr_, va.x, ar4[0]); ar4[0] = fmaf(-si_, va.y, ar4[0]);
    ai4[0] = fmaf(sr_, va.y, ai4[0]); ai4[0] = fmaf(si_, va.x, ai4[0]);
    ar4[1] = fmaf(sr_, va.z, ar4[1]); ar4[1] = fmaf(-si_, va.w, ar4[1]);
    ai4[1] = fmaf(sr_, va.w, ai4[1]); ai4[1] = fmaf(si_, va.z, ai4[1]);
    ar4[2] = fmaf(sr_, vb2.x, ar4[2]); ar4[2] = fmaf(-si_, vb2.y, ar4[2]);
    ai4[2] = fmaf(sr_, vb2.y, ai4[2]); ai4[2] = fmaf(si_, vb2.x, ai4[2]);
    ar4[3] = fmaf(sr_, vb2.z, ar4[3]); ar4[3] = fmaf(-si_, vb2.w, ar4[3]);
    ai4[3] = fmaf(sr_, vb2.w, ai4[3]); ai4[3] = fmaf(si_, vb2.z, ai4[3]);
  }
  int fbin = mq * 16 + m;
  float cf = (fbin == 0 ? 1.0f : 2.0f) / 4096.0f;
#pragma unroll
  for (int c = 0; c < 4; ++c) {
    int d = 4 * d0 + c;
    ypt[((size_t)bh * 64 + d) * 128 + 2 * fbin] = f2bfu(cf * ar4[c]);
    ypt[((size_t)bh * 64 + d) * 128 + 2 * fbin + 1] = f2bfu(cf * ai4[c]);
  }
}

// ---------------------------------------------------------------- irfft (bf16 MFMA GEMM)
// grid 4096 = 64 bh * 64 lchunk ; block 256 (4 waves). out[l][d] = sum_k btT[l][k]*ypt[d][k]
__global__ __launch_bounds__(256) void irfft_mfma(
    const unsigned short* __restrict__ ypt,
    const unsigned short* __restrict__ btT, float* __restrict__ out) {
  int bh = blockIdx.x >> 6, lc = blockIdx.x & 63;
  int t = threadIdx.x;
  int lane = t & 63, w = t >> 6;
  int l15 = lane & 15, qd = lane >> 4;

  __shared__ __align__(16) unsigned short A[2 * 64 * 72];  // [khalf][l][k64]
  __shared__ __align__(16) unsigned short Bm[2 * 64 * 72]; // [khalf][d][k64]

#pragma unroll
  for (int j = 0; j < 4; ++j) {
    int u = t + 256 * j;  // < 1024
    int row = u >> 4, seg = u & 15;
    int kh = seg >> 3, s8 = seg & 7;
    *(float4*)&A[kh * 4608 + row * 72 + s8 * 8] =
        *(const float4*)&btT[(size_t)(lc * 64 + row) * 128 + seg * 8];
    *(float4*)&Bm[kh * 4608 + row * 72 + s8 * 8] =
        *(const float4*)&ypt[(size_t)(bh * 64 + row) * 128 + seg * 8];
  }
  __syncthreads();

  f32x4 acc[4];
#pragma unroll
  for (int nt = 0; nt < 4; ++nt) acc[nt] = (f32x4){0.f, 0.f, 0.f, 0.f};

#pragma unroll
  for (int kh = 0; kh < 2; ++kh)
#pragma unroll
    for (int ks = 0; ks < 2; ++ks) {
      bf16x8 af =
          *(const bf16x8*)&A[kh * 4608 + (w * 16 + l15) * 72 + ks * 32 + qd * 8];
#pragma unroll
      for (int nt = 0; nt < 4; ++nt) {
        bf16x8 bf =
            *(const bf16x8*)&Bm[kh * 4608 + (nt * 16 + l15) * 72 + ks * 32 +
                                qd * 8];
        acc[nt] = __builtin_amdgcn_mfma_f32_16x16x32_bf16(af, bf, acc[nt], 0, 0, 0);
      }
    }

  float* obase = out + ((size_t)bh * 4096 + lc * 64) * 64;
  int row0 = w * 16 + qd * 4;
#pragma unroll
  for (int nt = 0; nt < 4; ++nt) {
    int col = nt * 16 + l15;
#pragma unroll
    for (int r = 0; r < 4; ++r) obase[(row0 + r) * 64 + col] = acc[nt][r];
  }
}

extern "C" void kernel_launch(void* const* d_in, const int* in_sizes, int n_in,
                              void* d_out, int out_size, void* d_ws,
                              size_t ws_size, hipStream_t stream) {
  const float* q = (const float*)d_in[0];
  const float* k = (const float*)d_in[1];
  const float* v = (const float*)d_in[2];
  const int* iq = (const int*)d_in[3];
  const int* ik = (const int*)d_in[4];
  const int* iv = (const int*)d_in[5];
  char* ws = (char*)d_ws;
  unsigned short* btT = (unsigned short*)ws;
  unsigned short* ypt = (unsigned short*)(ws + 1048576);
  float* ftQK = (float*)(ws + 2097152);
  unsigned short* ftV = (unsigned short*)(ws + 18874368);
  unsigned short* whi = (unsigned short*)(ws + 23068672);
  unsigned short* wlo = (unsigned short*)(ws + 26214400);
  float* out = (float*)d_out;

  hipLaunchKernelGGL(init_btT, dim3(2048), dim3(256), 0, stream, btT);
  hipLaunchKernelGGL(init_w, dim3(6144), dim3(256), 0, stream, whi, wlo, iq,
                     ik, iv);
  hipLaunchKernelGGL(dft_mfma, dim3(768), dim3(256), 0, stream, q, k, v, whi,
                     wlo, ftQK, ftV);
  hipLaunchKernelGGL(attn, dim3(256), dim3(256), 0, stream, ftQK, ftV, ypt);
  hipLaunchKernelGGL(irfft_mfma, dim3(4096), dim3(256), 0, stream, ypt, btT,
                     out);
}